// Round 3
// baseline (1002.042 us; speedup 1.0000x reference)
//
#include <hip/hip_runtime.h>

#define LN_EPS 1e-5f

typedef __bf16 bf16x8 __attribute__((ext_vector_type(8)));
typedef unsigned short ushort8v __attribute__((ext_vector_type(8)));
typedef float f32x4 __attribute__((ext_vector_type(4)));

__device__ __forceinline__ float bf16_to_f(unsigned short u) {
    unsigned int x = ((unsigned int)u) << 16;
    return __builtin_bit_cast(float, x);
}
__device__ __forceinline__ unsigned short f_to_bf16(float f) {
    unsigned int u = __builtin_bit_cast(unsigned int, f);
    u += 0x7FFFu + ((u >> 16) & 1u);   // round-to-nearest-even
    return (unsigned short)(u >> 16);
}
__device__ __forceinline__ int idx_at(const int* base, int i, int is64) {
    return is64 ? base[(long long)i << 1] : base[i];   // int64 LE: low word holds value
}

// dtype-polymorphic accessors ------------------------------------------------
template<int BF16>
__device__ __forceinline__ bf16x8 load_frag(const void* base, size_t off) {
    if (BF16) {
        return *(const bf16x8*)((const unsigned short*)base + off);
    } else {
        const float* p = (const float*)base + off;
        f32x4 a = *(const f32x4*)p;
        f32x4 b = *(const f32x4*)(p + 4);
        ushort8v u;
        u[0] = f_to_bf16(a[0]); u[1] = f_to_bf16(a[1]);
        u[2] = f_to_bf16(a[2]); u[3] = f_to_bf16(a[3]);
        u[4] = f_to_bf16(b[0]); u[5] = f_to_bf16(b[1]);
        u[6] = f_to_bf16(b[2]); u[7] = f_to_bf16(b[3]);
        return __builtin_bit_cast(bf16x8, u);
    }
}
template<int BF16>
__device__ __forceinline__ float load_sc(const void* base, size_t i) {
    return BF16 ? bf16_to_f(((const unsigned short*)base)[i]) : ((const float*)base)[i];
}
template<int BF16>
__device__ __forceinline__ void store_out(void* out, size_t i, float v) {
    if (BF16) ((unsigned short*)out)[i] = f_to_bf16(v);
    else      ((float*)out)[i] = v;
}

// ---------------------------------------------------------------------------
// flags[0] = edge_index is int64 (1) or int32 (0)
// flags[1] = float buffers are bf16 (1) or fp32 (0)
// ---------------------------------------------------------------------------
__global__ void detect_kernel(const unsigned short* __restrict__ xu,
                              const unsigned int* __restrict__ ei,
                              int N, int* __restrict__ flags)
{
    const int t = threadIdx.x;          // 64 threads
    unsigned short u = xu[2 * t];
    int e = (u >> 7) & 0xFF;
    int okb = (e >= 0x60 && e <= 0x8A) ? 1 : 0;
    unsigned long long bb = __ballot(okb);
    unsigned int lo = ei[2 * t], hi = ei[2 * t + 1];
    int ok64 = (hi == 0u && lo < (unsigned int)N) ? 1 : 0;
    unsigned long long b64 = __ballot(ok64);
    if (t == 0) {
        flags[1] = (__popcll(bb) >= 48) ? 1 : 0;
        flags[0] = (b64 == ~0ull) ? 1 : 0;
    }
}

// ---------------------------------------------------------------------------
// prep_all: 3 independent sections by blockIdx
//   A: zero sumbuf+ecnt (zn4 f32x4 stores)
//   B: fp32 path: convert x -> bf16 xb (n8 groups of 8)
//   C: transpose W -> bf16 W^T (32768 elems)
// ---------------------------------------------------------------------------
__global__ __launch_bounds__(256) void prep_all(
    const void* __restrict__ x, const void* __restrict__ Wm,
    const void* __restrict__ Wu,
    float* __restrict__ zbase, int zn4, int zb,
    unsigned short* __restrict__ xb, int n8, int cb,
    unsigned short* __restrict__ WmT, unsigned short* __restrict__ WuT,
    const int* __restrict__ flags)
{
    const int bf16 = flags[1];
    const int b = blockIdx.x;
    const int t = threadIdx.x;
    if (b < zb) {
        int i = b * 256 + t;
        if (i < zn4) {
            f32x4 z = {0.f, 0.f, 0.f, 0.f};
            ((f32x4*)zbase)[i] = z;
        }
    } else if (b < zb + cb) {
        if (bf16) return;
        int i = (b - zb) * 256 + t;
        if (i >= n8) return;
        const float* p = (const float*)x + (size_t)i * 8;
        f32x4 a = *(const f32x4*)p;
        f32x4 v = *(const f32x4*)(p + 4);
        ushort8v u;
        u[0] = f_to_bf16(a[0]); u[1] = f_to_bf16(a[1]);
        u[2] = f_to_bf16(a[2]); u[3] = f_to_bf16(a[3]);
        u[4] = f_to_bf16(v[0]); u[5] = f_to_bf16(v[1]);
        u[6] = f_to_bf16(v[2]); u[7] = f_to_bf16(v[3]);
        *(ushort8v*)(xb + (size_t)i * 8) = u;
    } else {
        int idx = (b - zb - cb) * 256 + t;   // 0 .. 32767
        if (idx >= 32768) return;
        int k = idx >> 7;
        int n = idx & 127;
        unsigned short wm, wu;
        if (bf16) {
            wm = ((const unsigned short*)Wm)[idx];
            wu = ((const unsigned short*)Wu)[idx];
        } else {
            wm = f_to_bf16(((const float*)Wm)[idx]);
            wu = f_to_bf16(((const float*)Wu)[idx]);
        }
        WmT[n * 256 + k] = wm;
        WuT[n * 256 + k] = wu;
    }
}

// ---------------------------------------------------------------------------
// Counting sort of edges by dst: histogram -> 2-level scan -> rank scatter.
// ---------------------------------------------------------------------------
__global__ __launch_bounds__(256) void hist_kernel(
    const int* __restrict__ eidx, int* __restrict__ ecnt,
    const int* __restrict__ flags, int E)
{
    int e = blockIdx.x * 256 + threadIdx.x;
    if (e >= E) return;
    const int is64 = flags[0];
    const int* dstp = eidx + (is64 ? 2 * E : E);
    atomicAdd(&ecnt[idx_at(dstp, e, is64)], 1);
}

// block b sums ecnt[b*1024 .. b*1024+1023] -> bsum[b]
__global__ __launch_bounds__(256) void scan_partial(
    const int* __restrict__ ecnt, int* __restrict__ bsum, int N)
{
    __shared__ int red[256];
    const int t = threadIdx.x;
    const int base = blockIdx.x * 1024 + t * 4;
    int s = 0;
    if (base + 3 < N) {
        int4 v = *(const int4*)(ecnt + base);
        s = v.x + v.y + v.z + v.w;
    } else {
        for (int j = 0; j < 4; ++j) if (base + j < N) s += ecnt[base + j];
    }
    red[t] = s;
    __syncthreads();
    for (int ofs = 128; ofs > 0; ofs >>= 1) {
        if (t < ofs) red[t] += red[t + ofs];
        __syncthreads();
    }
    if (t == 0) bsum[blockIdx.x] = red[0];
}

// per-block exclusive scan; block base computed inline from bsum (nb small)
__global__ __launch_bounds__(256) void scan_final(
    const int* __restrict__ ecnt, const int* __restrict__ bsum,
    int* __restrict__ cursor, int N)
{
    __shared__ int tsum[256];
    const int t = threadIdx.x;
    int bbase = 0;
    for (int i = 0; i < (int)blockIdx.x; ++i) bbase += bsum[i];
    const int base = blockIdx.x * 1024 + t * 4;
    int v0 = 0, v1 = 0, v2 = 0, v3 = 0;
    if (base + 3 < N) {
        int4 u = *(const int4*)(ecnt + base);
        v0 = u.x; v1 = u.y; v2 = u.z; v3 = u.w;
    } else {
        if (base + 0 < N) v0 = ecnt[base + 0];
        if (base + 1 < N) v1 = ecnt[base + 1];
        if (base + 2 < N) v2 = ecnt[base + 2];
    }
    tsum[t] = v0 + v1 + v2 + v3;
    __syncthreads();
    for (int ofs = 1; ofs < 256; ofs <<= 1) {
        int val = tsum[t];
        int add = (t >= ofs) ? tsum[t - ofs] : 0;
        __syncthreads();
        tsum[t] = val + add;
        __syncthreads();
    }
    int excl = (t == 0 ? 0 : tsum[t - 1]) + bbase;
    int c0 = excl, c1 = c0 + v0, c2 = c1 + v1, c3 = c2 + v2;
    if (base + 3 < N) {
        int4 o = {c0, c1, c2, c3};
        *(int4*)(cursor + base) = o;
    } else {
        if (base + 0 < N) cursor[base + 0] = c0;
        if (base + 1 < N) cursor[base + 1] = c1;
        if (base + 2 < N) cursor[base + 2] = c2;
    }
}

// pack (edge_id, src, dst) into one int4 -> single 16B scattered store
__global__ __launch_bounds__(256) void scatter_kernel(
    const int* __restrict__ eidx, int* __restrict__ cursor,
    int4* __restrict__ sed, const int* __restrict__ flags, int E)
{
    int e = blockIdx.x * 256 + threadIdx.x;
    if (e >= E) return;
    const int is64 = flags[0];
    const int* srcp = eidx;
    const int* dstp = eidx + (is64 ? 2 * E : E);
    int d = idx_at(dstp, e, is64);
    int s = idx_at(srcp, e, is64);
    int pos = atomicAdd(&cursor[d], 1);
    int4 v = {e, s, d, 0};
    sed[pos] = v;
}

// ---------------------------------------------------------------------------
// Edge body (dst-sorted): 64 sorted edges / block, 4 waves; wave w owns cols
// [w*32, w*32+32). Phase 1 (barrier-free): msg -> msgbuf LDS (64x130 f32,
// 33.5 KB -> 4 blocks/CU). Phase 2 (one barrier): 2-way segmented reduce.
// ---------------------------------------------------------------------------
template<int BF16>
__device__ __forceinline__ void edge_body(
    const unsigned short* __restrict__ xb,     // bf16 x (xb scratch or orig)
    const void* __restrict__ ea, const unsigned short* __restrict__ WmT,
    const void* __restrict__ b_msg,
    float* __restrict__ sumbuf,
    const int4* __restrict__ sed, int E)
{
    __shared__ float msgbuf[64][130];
    __shared__ int dS[64];

    const int pbase = blockIdx.x * 64;
    const int tid  = threadIdx.x;
    const int w    = tid >> 6;
    const int l    = tid & 63;
    const int m    = l & 15;
    const int quad = l >> 4;
    int valid = E - pbase; if (valid > 64) valid = 64;

    if (tid < 64) {
        int p = pbase + tid;
        dS[tid] = sed[p < E ? p : E - 1].z;
    }

    // prefetch per-lane edge ids + srcs (independent coalesced loads)
    int my_e[4], my_s[4];
#pragma unroll
    for (int mt = 0; mt < 4; ++mt) {
        int p = pbase + mt * 16 + m;
        if (p >= E) p = E - 1;
        int4 v = sed[p];
        my_e[mt] = v.x;
        my_s[mt] = v.y;
    }

    bf16x8 bfrag[2][8];
#pragma unroll
    for (int nt = 0; nt < 2; ++nt) {
        const unsigned short* p = WmT + (w * 32 + nt * 16 + m) * 256 + quad * 8;
#pragma unroll
        for (int kk = 0; kk < 8; ++kk)
            bfrag[nt][kk] = *(const bf16x8*)(p + kk * 32);
    }
    const float bias0 = load_sc<BF16>(b_msg, w * 32 + m);
    const float bias1 = load_sc<BF16>(b_msg, w * 32 + 16 + m);

#pragma unroll
    for (int mt = 0; mt < 4; ++mt) {
        const size_t xoff = (size_t)my_s[mt] * 128 + quad * 8;
        const size_t eoff = (size_t)my_e[mt] * 128 + quad * 8;

        f32x4 acc0 = {0.f, 0.f, 0.f, 0.f};
        f32x4 acc1 = {0.f, 0.f, 0.f, 0.f};
#pragma unroll
        for (int kk = 0; kk < 4; ++kk) {
            bf16x8 af = *(const bf16x8*)(xb + xoff + kk * 32);
            acc0 = __builtin_amdgcn_mfma_f32_16x16x32_bf16(af, bfrag[0][kk], acc0, 0, 0, 0);
            acc1 = __builtin_amdgcn_mfma_f32_16x16x32_bf16(af, bfrag[1][kk], acc1, 0, 0, 0);
        }
#pragma unroll
        for (int kk = 0; kk < 4; ++kk) {
            bf16x8 af = load_frag<BF16>(ea, eoff + kk * 32);
            acc0 = __builtin_amdgcn_mfma_f32_16x16x32_bf16(af, bfrag[0][kk + 4], acc0, 0, 0, 0);
            acc1 = __builtin_amdgcn_mfma_f32_16x16x32_bf16(af, bfrag[1][kk + 4], acc1, 0, 0, 0);
        }

#pragma unroll
        for (int i = 0; i < 4; ++i) {
            float v0 = acc0[i] + bias0; v0 = v0 > 0.f ? v0 : 0.f;
            float v1 = acc1[i] + bias1; v1 = v1 > 0.f ? v1 : 0.f;
            const int row = mt * 16 + quad * 4 + i;
            msgbuf[row][w * 32 + m]      = v0;
            msgbuf[row][w * 32 + 16 + m] = v1;
        }
    }
    __syncthreads();

    // phase 2: segmented reduce, rows split in two halves for 2x parallelism
    const int half = tid >> 7;
    const int col  = tid & 127;
    const int r0 = half * 32;
    int r1 = r0 + 32; if (r1 > valid) r1 = valid;
    if (r0 < r1) {
        int   cur_d = dS[r0];
        float s     = msgbuf[r0][col];
        int   first = 1;
        for (int r = r0 + 1; r < r1; ++r) {
            float v = msgbuf[r][col];
            int   d = dS[r];
            if (d == cur_d) {
                s += v;
            } else {
                float* p = &sumbuf[(size_t)cur_d * 128 + col];
                if (first) { atomicAdd(p, s); first = 0; }
                else       { *p = s; }          // interior segment: complete
                cur_d = d; s = v;
            }
        }
        atomicAdd(&sumbuf[(size_t)cur_d * 128 + col], s);  // may span halves/blocks
    }
}

__global__ __launch_bounds__(256, 4) void edge_kernel(
    const unsigned short* __restrict__ xb, const void* __restrict__ x,
    const void* __restrict__ ea, const unsigned short* __restrict__ WmT,
    const void* __restrict__ b_msg, float* __restrict__ sumbuf,
    const int4* __restrict__ sed, const int* __restrict__ flags, int E)
{
    if (flags[1]) edge_body<1>((const unsigned short*)x, ea, WmT, b_msg, sumbuf, sed, E);
    else          edge_body<0>(xb,                       ea, WmT, b_msg, sumbuf, sed, E);
}

// ---------------------------------------------------------------------------
// Node body: 64 nodes / block, 4 waves; wave w owns cols [w*32, w*32+32).
// h = [x | mean_msg] @ W_upd + b_upd; LayerNorm; out = relu(h_ln + x).
// ---------------------------------------------------------------------------
template<int BF16>
__device__ __forceinline__ void node_body(
    const void* __restrict__ x, const unsigned short* __restrict__ xbn,
    const float* __restrict__ sumbuf, const int* __restrict__ counts,
    const unsigned short* __restrict__ WuT, const void* __restrict__ b_upd,
    const void* __restrict__ gamma_, const void* __restrict__ beta_,
    void* __restrict__ out, int N)
{
    __shared__ float redS[4][64];
    __shared__ float redQ[4][64];
    __shared__ float muS[64];
    __shared__ float rsS[64];

    const int rbase = blockIdx.x * 64;
    const int tid  = threadIdx.x;
    const int w    = tid >> 6;
    const int l    = tid & 63;
    const int m    = l & 15;
    const int quad = l >> 4;

    bf16x8 bfrag[2][8];
#pragma unroll
    for (int nt = 0; nt < 2; ++nt) {
        const unsigned short* p = WuT + (w * 32 + nt * 16 + m) * 256 + quad * 8;
#pragma unroll
        for (int kk = 0; kk < 8; ++kk)
            bfrag[nt][kk] = *(const bf16x8*)(p + kk * 32);
    }
    const float bias0 = load_sc<BF16>(b_upd, w * 32 + m);
    const float bias1 = load_sc<BF16>(b_upd, w * 32 + 16 + m);

    f32x4 acc[4][2];

    for (int mt = 0; mt < 4; ++mt) {
        int r = rbase + mt * 16 + m;
        int rc = r < N ? r : N - 1;
        const size_t xoff = (size_t)rc * 128 + quad * 8;
        const float* srow = sumbuf + (size_t)rc * 128 + quad * 8;
        const float rcp = 1.0f / fmaxf((float)counts[rc], 1.0f);

        f32x4 a0 = {0.f, 0.f, 0.f, 0.f};
        f32x4 a1 = {0.f, 0.f, 0.f, 0.f};
#pragma unroll
        for (int kk = 0; kk < 4; ++kk) {
            bf16x8 af = *(const bf16x8*)(xbn + xoff + kk * 32);
            a0 = __builtin_amdgcn_mfma_f32_16x16x32_bf16(af, bfrag[0][kk], a0, 0, 0, 0);
            a1 = __builtin_amdgcn_mfma_f32_16x16x32_bf16(af, bfrag[1][kk], a1, 0, 0, 0);
        }
#pragma unroll
        for (int kk = 0; kk < 4; ++kk) {
            const float* sp = srow + kk * 32;
            ushort8v uu;
#pragma unroll
            for (int j = 0; j < 8; ++j) uu[j] = f_to_bf16(sp[j] * rcp);
            bf16x8 av = __builtin_bit_cast(bf16x8, uu);
            a0 = __builtin_amdgcn_mfma_f32_16x16x32_bf16(av, bfrag[0][kk + 4], a0, 0, 0, 0);
            a1 = __builtin_amdgcn_mfma_f32_16x16x32_bf16(av, bfrag[1][kk + 4], a1, 0, 0, 0);
        }

        float ps[4], qs[4];
#pragma unroll
        for (int i = 0; i < 4; ++i) {
            a0[i] += bias0;
            a1[i] += bias1;
            ps[i] = a0[i] + a1[i];
            qs[i] = a0[i] * a0[i] + a1[i] * a1[i];
        }
        acc[mt][0] = a0;
        acc[mt][1] = a1;

#pragma unroll
        for (int s = 1; s < 16; s <<= 1) {
#pragma unroll
            for (int i = 0; i < 4; ++i) {
                ps[i] += __shfl_xor(ps[i], s, 64);
                qs[i] += __shfl_xor(qs[i], s, 64);
            }
        }
        if (m == 0) {
#pragma unroll
            for (int i = 0; i < 4; ++i) {
                redS[w][mt * 16 + quad * 4 + i] = ps[i];
                redQ[w][mt * 16 + quad * 4 + i] = qs[i];
            }
        }
    }
    __syncthreads();

    if (tid < 64) {
        float s = redS[0][tid] + redS[1][tid] + redS[2][tid] + redS[3][tid];
        float q = redQ[0][tid] + redQ[1][tid] + redQ[2][tid] + redQ[3][tid];
        float mu = s * (1.0f / 128.0f);
        float var = q * (1.0f / 128.0f) - mu * mu;
        muS[tid] = mu;
        rsS[tid] = rsqrtf(var + LN_EPS);
    }
    __syncthreads();

    const float g0  = load_sc<BF16>(gamma_, w * 32 + m);
    const float be0 = load_sc<BF16>(beta_,  w * 32 + m);
    const float g1  = load_sc<BF16>(gamma_, w * 32 + 16 + m);
    const float be1 = load_sc<BF16>(beta_,  w * 32 + 16 + m);

    for (int mt = 0; mt < 4; ++mt) {
#pragma unroll
        for (int i = 0; i < 4; ++i) {
            const int ridx = mt * 16 + quad * 4 + i;
            const int r = rbase + ridx;
            if (r < N) {
                const float mu = muS[ridx];
                const float rs = rsS[ridx];
                const size_t c0 = (size_t)r * 128 + w * 32 + m;
                const size_t c1 = c0 + 16;
                float v0 = (acc[mt][0][i] - mu) * rs * g0 + be0 + load_sc<BF16>(x, c0);
                float v1 = (acc[mt][1][i] - mu) * rs * g1 + be1 + load_sc<BF16>(x, c1);
                store_out<BF16>(out, c0, v0 > 0.f ? v0 : 0.f);
                store_out<BF16>(out, c1, v1 > 0.f ? v1 : 0.f);
            }
        }
    }
}

__global__ __launch_bounds__(256) void node_kernel(
    const void* __restrict__ x, const unsigned short* __restrict__ xb,
    const float* __restrict__ sumbuf, const int* __restrict__ counts,
    const unsigned short* __restrict__ WuT, const void* __restrict__ b_upd,
    const void* __restrict__ gamma_, const void* __restrict__ beta_,
    void* __restrict__ out, const int* __restrict__ flags, int N)
{
    if (flags[1]) node_body<1>(x, (const unsigned short*)x, sumbuf, counts,
                               WuT, b_upd, gamma_, beta_, out, N);
    else          node_body<0>(x, xb, sumbuf, counts,
                               WuT, b_upd, gamma_, beta_, out, N);
}

// ---------------------------------------------------------------------------
extern "C" void kernel_launch(void* const* d_in, const int* in_sizes, int n_in,
                              void* d_out, int out_size, void* d_ws, size_t ws_size,
                              hipStream_t stream)
{
    const void* x  = d_in[0];
    const int*  ei = (const int*)d_in[1];
    const void* ea = d_in[2];
    const void* Wm = d_in[3];
    const void* bm = d_in[4];
    const void* Wu = d_in[5];
    const void* bu = d_in[6];
    const void* gm = d_in[7];
    const void* bt = d_in[8];

    const int N = in_sizes[0] / 128;
    const int E = in_sizes[2] / 128;

    // ws layout: flags[4] | sumbuf N*128 f32 | ecnt N i32 | cursor N i32 |
    //            bsum 256 i32 | sed E int4 | xb N*128 bf16 | WmT | WuT
    char* ws = (char*)d_ws;
    int*   flags    = (int*)ws;
    float* sumbuf   = (float*)(ws + 16);
    int*   ecnt     = (int*)(ws + 16 + (size_t)N * 512);
    int*   cursor   = ecnt + N;
    int*   bsum     = cursor + N;
    int4*  sed      = (int4*)(bsum + 256);
    unsigned short* xb  = (unsigned short*)(sed + E);
    unsigned short* WmT = xb + (size_t)N * 128;
    unsigned short* WuT = WmT + 256 * 128;

    detect_kernel<<<1, 64, 0, stream>>>((const unsigned short*)x,
                                        (const unsigned int*)ei, N, flags);

    // fused prep: zero sumbuf+ecnt | convert x->bf16 | transpose weights
    const int zn4 = (N * 129 + 3) / 4;
    const int zb  = (zn4 + 255) / 256;
    const int n8  = N * 16;
    const int cb  = (n8 + 255) / 256;
    const int tb  = 128;
    prep_all<<<zb + cb + tb, 256, 0, stream>>>(x, Wm, Wu, sumbuf, zn4, zb,
                                               xb, n8, cb, WmT, WuT, flags);

    const int eb256 = (E + 255) / 256;
    hist_kernel<<<eb256, 256, 0, stream>>>(ei, ecnt, flags, E);

    const int nb = (N + 1023) / 1024;
    scan_partial<<<nb, 256, 0, stream>>>(ecnt, bsum, N);
    scan_final<<<nb, 256, 0, stream>>>(ecnt, bsum, cursor, N);

    scatter_kernel<<<eb256, 256, 0, stream>>>(ei, cursor, sed, flags, E);

    const int eblocks = (E + 63) / 64;
    edge_kernel<<<eblocks, 256, 0, stream>>>(xb, x, ea, WmT, bm, sumbuf, sed, flags, E);

    const int nblocks = (N + 63) / 64;
    node_kernel<<<nblocks, 256, 0, stream>>>(x, xb, sumbuf, ecnt, WuT, bu, gm, bt,
                                             d_out, flags, N);
}